// Round 4
// baseline (400.636 us; speedup 1.0000x reference)
//
#include <hip/hip_runtime.h>

typedef unsigned short u16;
typedef unsigned int u32;
typedef __bf16 bf16x8 __attribute__((ext_vector_type(8)));
typedef float f32x4 __attribute__((ext_vector_type(4)));

#define S_LEN 4096
#define DM 256

__device__ __forceinline__ u16 f2b(float f) {
  u32 u = __builtin_bit_cast(u32, f);
  u = (u + 0x7FFFu + ((u >> 16) & 1u)) >> 16;
  return (u16)u;
}
__device__ __forceinline__ float b2f(u16 b) {
  return __builtin_bit_cast(float, (u32)b << 16);
}

__device__ __forceinline__ f32x4 mfma16(bf16x8 a, bf16x8 b, f32x4 c) {
  return __builtin_amdgcn_mfma_f32_16x16x32_bf16(a, b, c, 0, 0, 0);
}

// async 16B global->LDS (lane writes lds_base + lane*16)
__device__ __forceinline__ void gl_lds16(const u16* g, u16* l) {
  __builtin_amdgcn_global_load_lds(
      (const __attribute__((address_space(1))) u32*)g,
      (__attribute__((address_space(3))) u32*)l, 16, 0, 0);
}

// C[M][N] = (A[M][K] @ B[N][K]^T + bias) * scale   (NT gemm, K contiguous both sides)
template <int TIN_F32, int TOUT_F32, int BIAS_MODE>
__global__ __launch_bounds__(256, 2) void gemm_nt_kernel(
    const void* __restrict__ Ap, const void* __restrict__ Bp,
    void* __restrict__ Cp, const float* __restrict__ bias, float scale,
    int M, int N, int K, int lda, int ldb, int ldc,
    long sA, long sB, long sC) {
  __shared__ u16 As[64][72];
  __shared__ u16 Bs[64][72];
  const int tid = threadIdx.x;
  const int w = tid >> 6, ln = tid & 63, lg = ln >> 4, ll = ln & 15;
  const int m0 = blockIdx.x * 64, n0 = blockIdx.y * 64;
  const long zA = (long)blockIdx.z * sA, zB = (long)blockIdx.z * sB,
             zC = (long)blockIdx.z * sC;

  const f32x4 fzero = {0.f, 0.f, 0.f, 0.f};
  f32x4 acc[4];
#pragma unroll
  for (int i = 0; i < 4; ++i) acc[i] = fzero;

  const int srow = tid >> 2, scb = (tid & 3) * 16;
  const int nk = (K + 63) >> 6;
  for (int kc = 0; kc < nk; ++kc) {
    const int k0 = kc * 64;
    if (TIN_F32) {
      {
        const float* src = (const float*)Ap + zA + (size_t)(m0 + srow) * lda + k0 + scb;
        u16 t[16];
        if (k0 + 64 <= K) {
#pragma unroll
          for (int i = 0; i < 16; ++i) t[i] = f2b(src[i]);
        } else {
#pragma unroll
          for (int i = 0; i < 16; ++i) {
            int gk = k0 + scb + i;
            t[i] = (gk < K) ? f2b(src[i]) : (u16)0;
          }
        }
#pragma unroll
        for (int i = 0; i < 16; ++i) As[srow][scb + i] = t[i];
      }
      {
        const float* src = (const float*)Bp + zB + (size_t)(n0 + srow) * ldb + k0 + scb;
        u16 t[16];
        if (k0 + 64 <= K) {
#pragma unroll
          for (int i = 0; i < 16; ++i) t[i] = f2b(src[i]);
        } else {
#pragma unroll
          for (int i = 0; i < 16; ++i) {
            int gk = k0 + scb + i;
            t[i] = (gk < K) ? f2b(src[i]) : (u16)0;
          }
        }
#pragma unroll
        for (int i = 0; i < 16; ++i) Bs[srow][scb + i] = t[i];
      }
    } else {
      const u16* srcA = (const u16*)Ap + zA + (size_t)(m0 + srow) * lda + k0 + scb;
      *(bf16x8*)&As[srow][scb] = *(const bf16x8*)srcA;
      *(bf16x8*)&As[srow][scb + 8] = *(const bf16x8*)(srcA + 8);
      const u16* srcB = (const u16*)Bp + zB + (size_t)(n0 + srow) * ldb + k0 + scb;
      *(bf16x8*)&Bs[srow][scb] = *(const bf16x8*)srcB;
      *(bf16x8*)&Bs[srow][scb + 8] = *(const bf16x8*)(srcB + 8);
    }
    __syncthreads();
#pragma unroll
    for (int ks = 0; ks < 2; ++ks) {
      bf16x8 af = *(const bf16x8*)&As[w * 16 + ll][ks * 32 + lg * 8];
#pragma unroll
      for (int ct = 0; ct < 4; ++ct) {
        bf16x8 bfr = *(const bf16x8*)&Bs[ct * 16 + ll][ks * 32 + lg * 8];
        acc[ct] = mfma16(af, bfr, acc[ct]);
      }
    }
    __syncthreads();
  }

#pragma unroll
  for (int ct = 0; ct < 4; ++ct) {
#pragma unroll
    for (int j = 0; j < 4; ++j) {
      int row = m0 + w * 16 + lg * 4 + j;
      int col = n0 + ct * 16 + ll;
      float v = acc[ct][j];
      if (BIAS_MODE == 1) v += bias[col];
      if (BIAS_MODE == 2) v += bias[row];
      v *= scale;
      if (TOUT_F32)
        ((float*)Cp)[zC + (size_t)row * ldc + col] = v;
      else
        ((u16*)Cp)[zC + (size_t)row * ldc + col] = f2b(v);
    }
  }
}

// Wo_sum[d][e] = sum_h Wo[d][h*256+e]  (bf16)
__global__ void wos_kernel(const float* __restrict__ Wo, u16* __restrict__ WoS) {
  int d = blockIdx.x, e = threadIdx.x;
  const float* p = Wo + (size_t)d * 1024;
  WoS[(size_t)d * 256 + e] = f2b(p[e] + p[256 + e] + p[512 + e] + p[768 + e]);
}

// Flash attention, no-max softmax, raw int mask read in-kernel.
// Grid 512 linear, XCD-swizzled so each XCD owns one kv-chunk (K-chunk +
// V-columns stay L2-resident). 4 waves x 32 q-rows, KVBLK=64 staged
// double-buffered via global_load_lds (pre-swizzled source, linear LDS);
// two 32-kv sub-passes per tile; V read direct from global (L2 hit).
__global__ __launch_bounds__(256, 2) void flash_kernel(
    const u16* __restrict__ qh, const u16* __restrict__ kh,
    const u16* __restrict__ vhT, const int* __restrict__ mask,
    u16* __restrict__ Opart, float* __restrict__ Lpart) {
  __shared__ u16 kh_s[2][64 * 256];  // 64KB dbuf, 16B-chunk swz: cc ^= row&7
  __shared__ u16 p_s[4][32][40];     // 10KB per-wave P tile

  const int tid = threadIdx.x;
  const int w = tid >> 6, ln = tid & 63, lg = ln >> 4, ll = ln & 15;
  // XCD swizzle: consecutive hw blocks round-robin XCDs; remap so XCD i gets
  // logical ids [64i, 64i+64) = one kv-chunk (z), both batches, all q-blocks.
  const int wg = (blockIdx.x & 7) * 64 + (blockIdx.x >> 3);
  const int q0 = (wg & 31) * 128;
  const int b = (wg >> 5) & 1;
  const int h = wg >> 6;  // kv chunk (512 each)

  bf16x8 qf[2][8];
#pragma unroll
  for (int qg = 0; qg < 2; ++qg) {
    const u16* qp = qh + (size_t)(b * S_LEN + q0 + w * 32 + qg * 16 + ll) * DM + lg * 8;
#pragma unroll
    for (int ks = 0; ks < 8; ++ks) qf[qg][ks] = *(const bf16x8*)(qp + ks * 32);
  }

  const f32x4 fzero = {0.f, 0.f, 0.f, 0.f};
  f32x4 acc_o[2][16];
#pragma unroll
  for (int qg = 0; qg < 2; ++qg)
#pragma unroll
    for (int i = 0; i < 16; ++i) acc_o[qg][i] = fzero;
  float l_run[2][4] = {{0.f, 0.f, 0.f, 0.f}, {0.f, 0.f, 0.f, 0.f}};

  const u16* kbase = kh + (size_t)(b * S_LEN + h * 512) * DM;
  const u16* vbase = vhT + (size_t)b * DM * S_LEN + h * 512;
  const int* mbase = mask + ((size_t)(b * S_LEN + q0 + w * 32)) * S_LEN + h * 512;

  auto stage = [&](int t, int buf) {
#pragma unroll
    for (int i = 0; i < 8; ++i) {
      int c = i * 256 + tid;
      int row = c >> 5, ccl = c & 31;
      int ccg = ccl ^ (row & 7);  // pre-swizzled source, linear LDS dest
      gl_lds16(kbase + (size_t)(t * 64 + row) * DM + ccg * 8,
               &kh_s[buf][(i * 256 + w * 64) * 8]);
    }
  };

  stage(0, 0);
  __syncthreads();

  int cur = 0;
  for (int t = 0; t < 8; ++t) {
    if (t + 1 < 8) stage(t + 1, cur ^ 1);

#pragma unroll
    for (int sub = 0; sub < 2; ++sub) {
      const int kvb = t * 64 + sub * 32;
      // mask bits for this sub (independent loads; scheduler hoists early)
      int mv0[2][4], mv1[2][4];
#pragma unroll
      for (int qg = 0; qg < 2; ++qg)
#pragma unroll
        for (int j = 0; j < 4; ++j) {
          const int* mr = mbase + (size_t)(qg * 16 + lg * 4 + j) * S_LEN + kvb;
          mv0[qg][j] = mr[ll];
          mv1[qg][j] = mr[16 + ll];
        }

      f32x4 accs[2][2];
      accs[0][0] = fzero;
      accs[0][1] = fzero;
      accs[1][0] = fzero;
      accs[1][1] = fzero;
#pragma unroll
      for (int ks = 0; ks < 8; ++ks) {
#pragma unroll
        for (int half = 0; half < 2; ++half) {
          int krow = sub * 32 + half * 16 + ll;
          bf16x8 kf = *(const bf16x8*)&kh_s[cur][krow * 256 +
                                                (((ks * 4 + lg) ^ (krow & 7)) << 3)];
          accs[0][half] = mfma16(qf[0][ks], kf, accs[0][half]);
          accs[1][half] = mfma16(qf[1][ks], kf, accs[1][half]);
        }
      }

#pragma unroll
      for (int qg = 0; qg < 2; ++qg) {
#pragma unroll
        for (int j = 0; j < 4; ++j) {
          float p0 = mv0[qg][j] ? __expf(accs[qg][0][j]) : 0.f;
          float p1 = mv1[qg][j] ? __expf(accs[qg][1][j]) : 0.f;
          l_run[qg][j] += p0 + p1;
          int r = qg * 16 + lg * 4 + j;
          p_s[w][r][ll] = f2b(p0);
          p_s[w][r][16 + ll] = f2b(p1);
        }
      }
      bf16x8 pf0 = *(const bf16x8*)&p_s[w][ll][lg * 8];
      bf16x8 pf1 = *(const bf16x8*)&p_s[w][16 + ll][lg * 8];

#pragma unroll
      for (int dt = 0; dt < 16; ++dt) {
        const u16* vp = vbase + (size_t)(dt * 16 + ll) * S_LEN + kvb + lg * 8;
        bf16x8 vf = *(const bf16x8*)vp;
        acc_o[0][dt] = mfma16(pf0, vf, acc_o[0][dt]);
        acc_o[1][dt] = mfma16(pf1, vf, acc_o[1][dt]);
      }
    }
    __syncthreads();
    cur ^= 1;
  }

  // epilogue: reduce l across 16 ll-lanes, write partials
#pragma unroll
  for (int qg = 0; qg < 2; ++qg) {
#pragma unroll
    for (int j = 0; j < 4; ++j) {
      float l = l_run[qg][j];
      l += __shfl_xor(l, 1);
      l += __shfl_xor(l, 2);
      l += __shfl_xor(l, 4);
      l += __shfl_xor(l, 8);
      l_run[qg][j] = l;
    }
  }
  const size_t growb = (size_t)h * 8192 + (size_t)b * S_LEN + q0 + w * 32;
  if (ll == 0) {
#pragma unroll
    for (int qg = 0; qg < 2; ++qg)
#pragma unroll
      for (int j = 0; j < 4; ++j)
        Lpart[growb + qg * 16 + lg * 4 + j] = l_run[qg][j];
  }
#pragma unroll
  for (int qg = 0; qg < 2; ++qg)
#pragma unroll
    for (int dt = 0; dt < 16; ++dt)
#pragma unroll
      for (int j = 0; j < 4; ++j)
        Opart[(growb + qg * 16 + lg * 4 + j) * 256 + dt * 16 + ll] =
            f2b(acc_o[qg][dt][j]);
}

// sum the 8 chunk partials, normalize, emit per_head bf16
__global__ void combine_kernel(const u16* __restrict__ Opart,
                               const float* __restrict__ Lpart,
                               u16* __restrict__ ph) {
  const int r = blockIdx.x;
  const int d = threadIdx.x;
  float o = 0.f, l = 0.f;
#pragma unroll
  for (int s = 0; s < 8; ++s) {
    l += Lpart[(size_t)s * 8192 + r];
    o += b2f(Opart[((size_t)s * 8192 + r) * 256 + d]);
  }
  ph[(size_t)r * 256 + d] = f2b(o / l);
}

extern "C" void kernel_launch(void* const* d_in, const int* in_sizes, int n_in,
                              void* d_out, int out_size, void* d_ws, size_t ws_size,
                              hipStream_t stream) {
  const float* q = (const float*)d_in[0];
  const float* k = (const float*)d_in[1];
  const float* v = (const float*)d_in[2];
  const int* mask = (const int*)d_in[3];
  const float* Wq = (const float*)d_in[4];
  const float* bq = (const float*)d_in[5];
  const float* Wk = (const float*)d_in[6];
  const float* bk = (const float*)d_in[7];
  const float* Wv = (const float*)d_in[8];
  const float* bv = (const float*)d_in[9];
  const float* Wo = (const float*)d_in[10];
  const float* bo = (const float*)d_in[11];

  char* ws = (char*)d_ws;
  u16* qh = (u16*)(ws + 0);              //  4 MiB [2][4096][256]; reused as ph
  u16* kh = (u16*)(ws + 4194304);        //  4 MiB [2][4096][256]
  u16* vhT = (u16*)(ws + 8388608);       //  4 MiB [2][256][4096] (transposed)
  u16* WoS = (u16*)(ws + 12582912);      //  128 KiB [256][256]
  u16* Op = (u16*)(ws + 16908288);       // 32 MiB [8][8192][256] bf16 partials
  float* Lp = (float*)(ws + 50462720);   // 256 KiB [8][8192] f32 row sums

  dim3 blk(256);
  gemm_nt_kernel<1, 0, 1><<<dim3(128, 4, 1), blk, 0, stream>>>(
      q, Wq, qh, bq, 0.0625f, 8192, 256, 256, 256, 256, 256, 0, 0, 0);
  gemm_nt_kernel<1, 0, 1><<<dim3(128, 4, 1), blk, 0, stream>>>(
      k, Wk, kh, bk, 1.0f, 8192, 256, 264, 264, 264, 256, 0, 0, 0);
  gemm_nt_kernel<1, 0, 2><<<dim3(4, 64, 2), blk, 0, stream>>>(
      Wv, v, vhT, bv, 1.0f, 256, 4096, 256, 256, 256, 4096,
      0, (long)4096 * 256, (long)256 * 4096);
  wos_kernel<<<dim3(256), blk, 0, stream>>>(Wo, WoS);
  flash_kernel<<<dim3(512), blk, 0, stream>>>(qh, kh, vhT, mask, Op, Lp);
  combine_kernel<<<dim3(8192), blk, 0, stream>>>(Op, Lp, qh);
  gemm_nt_kernel<0, 1, 1><<<dim3(128, 4, 1), blk, 0, stream>>>(
      qh, WoS, d_out, bo, 1.0f, 8192, 256, 256, 256, 256, 256, 0, 0, 0);
}

// Round 5
// 381.599 us; speedup vs baseline: 1.0499x; 1.0499x over previous
//
#include <hip/hip_runtime.h>

typedef unsigned short u16;
typedef unsigned int u32;
typedef unsigned long long u64;
typedef __bf16 bf16x8 __attribute__((ext_vector_type(8)));
typedef float f32x4 __attribute__((ext_vector_type(4)));

#define S_LEN 4096
#define DM 256

__device__ __forceinline__ u16 f2b(float f) {
  u32 u = __builtin_bit_cast(u32, f);
  u = (u + 0x7FFFu + ((u >> 16) & 1u)) >> 16;
  return (u16)u;
}
__device__ __forceinline__ float b2f(u16 b) {
  return __builtin_bit_cast(float, (u32)b << 16);
}

__device__ __forceinline__ f32x4 mfma16(bf16x8 a, bf16x8 b, f32x4 c) {
  return __builtin_amdgcn_mfma_f32_16x16x32_bf16(a, b, c, 0, 0, 0);
}

// async 16B global->LDS (lane writes lds_base + lane*16)
__device__ __forceinline__ void gl_lds16(const u16* g, u16* l) {
  __builtin_amdgcn_global_load_lds(
      (const __attribute__((address_space(1))) u32*)g,
      (__attribute__((address_space(3))) u32*)l, 16, 0, 0);
}

// C[M][N] = (A[M][K] @ B[N][K]^T + bias) * scale   (NT gemm, K contiguous both sides)
template <int TIN_F32, int TOUT_F32, int BIAS_MODE>
__global__ __launch_bounds__(256, 2) void gemm_nt_kernel(
    const void* __restrict__ Ap, const void* __restrict__ Bp,
    void* __restrict__ Cp, const float* __restrict__ bias, float scale,
    int M, int N, int K, int lda, int ldb, int ldc,
    long sA, long sB, long sC) {
  __shared__ u16 As[64][72];
  __shared__ u16 Bs[64][72];
  const int tid = threadIdx.x;
  const int w = tid >> 6, ln = tid & 63, lg = ln >> 4, ll = ln & 15;
  const int m0 = blockIdx.x * 64, n0 = blockIdx.y * 64;
  const long zA = (long)blockIdx.z * sA, zB = (long)blockIdx.z * sB,
             zC = (long)blockIdx.z * sC;

  const f32x4 fzero = {0.f, 0.f, 0.f, 0.f};
  f32x4 acc[4];
#pragma unroll
  for (int i = 0; i < 4; ++i) acc[i] = fzero;

  const int srow = tid >> 2, scb = (tid & 3) * 16;
  const int nk = (K + 63) >> 6;
  for (int kc = 0; kc < nk; ++kc) {
    const int k0 = kc * 64;
    if (TIN_F32) {
      {
        const float* src = (const float*)Ap + zA + (size_t)(m0 + srow) * lda + k0 + scb;
        u16 t[16];
        if (k0 + 64 <= K) {
#pragma unroll
          for (int i = 0; i < 16; ++i) t[i] = f2b(src[i]);
        } else {
#pragma unroll
          for (int i = 0; i < 16; ++i) {
            int gk = k0 + scb + i;
            t[i] = (gk < K) ? f2b(src[i]) : (u16)0;
          }
        }
#pragma unroll
        for (int i = 0; i < 16; ++i) As[srow][scb + i] = t[i];
      }
      {
        const float* src = (const float*)Bp + zB + (size_t)(n0 + srow) * ldb + k0 + scb;
        u16 t[16];
        if (k0 + 64 <= K) {
#pragma unroll
          for (int i = 0; i < 16; ++i) t[i] = f2b(src[i]);
        } else {
#pragma unroll
          for (int i = 0; i < 16; ++i) {
            int gk = k0 + scb + i;
            t[i] = (gk < K) ? f2b(src[i]) : (u16)0;
          }
        }
#pragma unroll
        for (int i = 0; i < 16; ++i) Bs[srow][scb + i] = t[i];
      }
    } else {
      const u16* srcA = (const u16*)Ap + zA + (size_t)(m0 + srow) * lda + k0 + scb;
      *(bf16x8*)&As[srow][scb] = *(const bf16x8*)srcA;
      *(bf16x8*)&As[srow][scb + 8] = *(const bf16x8*)(srcA + 8);
      const u16* srcB = (const u16*)Bp + zB + (size_t)(n0 + srow) * ldb + k0 + scb;
      *(bf16x8*)&Bs[srow][scb] = *(const bf16x8*)srcB;
      *(bf16x8*)&Bs[srow][scb + 8] = *(const bf16x8*)(srcB + 8);
    }
    __syncthreads();
#pragma unroll
    for (int ks = 0; ks < 2; ++ks) {
      bf16x8 af = *(const bf16x8*)&As[w * 16 + ll][ks * 32 + lg * 8];
#pragma unroll
      for (int ct = 0; ct < 4; ++ct) {
        bf16x8 bfr = *(const bf16x8*)&Bs[ct * 16 + ll][ks * 32 + lg * 8];
        acc[ct] = mfma16(af, bfr, acc[ct]);
      }
    }
    __syncthreads();
  }

#pragma unroll
  for (int ct = 0; ct < 4; ++ct) {
#pragma unroll
    for (int j = 0; j < 4; ++j) {
      int row = m0 + w * 16 + lg * 4 + j;
      int col = n0 + ct * 16 + ll;
      float v = acc[ct][j];
      if (BIAS_MODE == 1) v += bias[col];
      if (BIAS_MODE == 2) v += bias[row];
      v *= scale;
      if (TOUT_F32)
        ((float*)Cp)[zC + (size_t)row * ldc + col] = v;
      else
        ((u16*)Cp)[zC + (size_t)row * ldc + col] = f2b(v);
    }
  }
}

// Wo_sum[d][e] = sum_h Wo[d][h*256+e]  (bf16)
__global__ void wos_kernel(const float* __restrict__ Wo, u16* __restrict__ WoS) {
  int d = blockIdx.x, e = threadIdx.x;
  const float* p = Wo + (size_t)d * 1024;
  WoS[(size_t)d * 256 + e] = f2b(p[e] + p[256 + e] + p[512 + e] + p[768 + e]);
}

// mask int32 -> bitmask (bit i of u64 group g of row r = mask[r][64g+i] != 0)
__global__ __launch_bounds__(256) void bitpack_kernel(const int* __restrict__ mask,
                                                      u32* __restrict__ mb) {
  const int ln = threadIdx.x & 63;
  const int gw = (int)((blockIdx.x * 256 + threadIdx.x) >> 6);
  const int nw = gridDim.x * 4;
  u64* mb64 = (u64*)mb;
  for (int it = gw; it < 131072; it += nw) {
    const int* p = mask + (size_t)it * 256 + ln;
    int v0 = p[0], v1 = p[64], v2 = p[128], v3 = p[192];
    u64 b0 = __ballot(v0 != 0);
    u64 b1 = __ballot(v1 != 0);
    u64 b2 = __ballot(v2 != 0);
    u64 b3 = __ballot(v3 != 0);
    if (ln < 4) {
      u64 val = ln == 0 ? b0 : (ln == 1 ? b1 : (ln == 2 ? b2 : b3));
      mb64[(size_t)it * 4 + ln] = val;
    }
  }
}

// Flash attention, no-max softmax, bitmask, V direct from global (L2-hot via
// XCD chunk pinning). 4 waves x 32 q-rows; K tiles (32 kv) double-buffered in
// LDS via global_load_lds (pre-swizzled source, linear dest). Grid 64*nslots,
// XCD-swizzled so each XCD owns 64*nslots/8 consecutive logical blocks
// (= nslots/8 kv-chunks -> K+V chunk stays in that XCD's L2).
__global__ __launch_bounds__(256, 3) void flash_kernel(
    const u16* __restrict__ qh, const u16* __restrict__ kh,
    const u16* __restrict__ vhT, const u32* __restrict__ mb,
    u16* __restrict__ Opart, float* __restrict__ Lpart,
    int ckv, int ntiles) {
  __shared__ u16 kh_s[2][32 * 256];  // 32KB dbuf, 16B-chunk swz: cc ^= row&7
  __shared__ u16 p_s[4][32][40];     // 10KB per-wave P tile

  const int tid = threadIdx.x;
  const int w = tid >> 6, ln = tid & 63, lg = ln >> 4, ll = ln & 15;
  const int nwg = gridDim.x;
  const int wg = ((int)blockIdx.x & 7) * (nwg >> 3) + ((int)blockIdx.x >> 3);
  const int q0 = (wg & 31) * 128;
  const int b = (wg >> 5) & 1;
  const int h = wg >> 6;  // kv chunk

  bf16x8 qf[2][8];
#pragma unroll
  for (int qg = 0; qg < 2; ++qg) {
    const u16* qp = qh + (size_t)(b * S_LEN + q0 + w * 32 + qg * 16 + ll) * DM + lg * 8;
#pragma unroll
    for (int ks = 0; ks < 8; ++ks) qf[qg][ks] = *(const bf16x8*)(qp + ks * 32);
  }

  const f32x4 fzero = {0.f, 0.f, 0.f, 0.f};
  f32x4 acc_o[2][16];
#pragma unroll
  for (int qg = 0; qg < 2; ++qg)
#pragma unroll
    for (int i = 0; i < 16; ++i) acc_o[qg][i] = fzero;
  float l_run[2][4] = {{0.f, 0.f, 0.f, 0.f}, {0.f, 0.f, 0.f, 0.f}};

  const u16* kbase = kh + (size_t)(b * S_LEN + h * ckv) * DM;
  const u16* vbase = vhT + (size_t)b * DM * S_LEN + h * ckv;
  const u32* mbase = mb + (size_t)(b * S_LEN + q0 + w * 32) * 128 + (h * ckv >> 5);

  auto stage = [&](int t, int buf) {
#pragma unroll
    for (int i = 0; i < 4; ++i) {
      int c = i * 256 + tid;
      int row = c >> 5, ccl = c & 31;
      int ccg = ccl ^ (row & 7);  // pre-swizzled source, linear LDS dest
      gl_lds16(kbase + (size_t)(t * 32 + row) * DM + ccg * 8,
               &kh_s[buf][(i * 256 + w * 64) * 8]);
    }
  };

  stage(0, 0);
  __syncthreads();

  int cur = 0;
  for (int t = 0; t < ntiles; ++t) {
    // bitmask words first (L2/L3-hot; covered by QK compute)
    u32 mw[2][4];
#pragma unroll
    for (int qg = 0; qg < 2; ++qg)
#pragma unroll
      for (int j = 0; j < 4; ++j)
        mw[qg][j] = mbase[(size_t)(qg * 16 + lg * 4 + j) * 128 + t];

    if (t + 1 < ntiles) stage(t + 1, cur ^ 1);

    f32x4 accs[2][2];
    accs[0][0] = fzero;
    accs[0][1] = fzero;
    accs[1][0] = fzero;
    accs[1][1] = fzero;
#pragma unroll
    for (int ks = 0; ks < 8; ++ks) {
#pragma unroll
      for (int half = 0; half < 2; ++half) {
        int krow = half * 16 + ll;
        bf16x8 kf = *(const bf16x8*)&kh_s[cur][krow * 256 +
                                              (((ks * 4 + lg) ^ (krow & 7)) << 3)];
        accs[0][half] = mfma16(qf[0][ks], kf, accs[0][half]);
        accs[1][half] = mfma16(qf[1][ks], kf, accs[1][half]);
      }
    }

#pragma unroll
    for (int qg = 0; qg < 2; ++qg) {
#pragma unroll
      for (int j = 0; j < 4; ++j) {
        u32 m = mw[qg][j];
        float p0 = ((m >> ll) & 1u) ? __expf(accs[qg][0][j]) : 0.f;
        float p1 = ((m >> (16 + ll)) & 1u) ? __expf(accs[qg][1][j]) : 0.f;
        l_run[qg][j] += p0 + p1;
        int r = qg * 16 + lg * 4 + j;
        p_s[w][r][ll] = f2b(p0);
        p_s[w][r][16 + ll] = f2b(p1);
      }
    }
    bf16x8 pf0 = *(const bf16x8*)&p_s[w][ll][lg * 8];
    bf16x8 pf1 = *(const bf16x8*)&p_s[w][16 + ll][lg * 8];

#pragma unroll
    for (int dt = 0; dt < 16; ++dt) {
      const u16* vp = vbase + (size_t)(dt * 16 + ll) * S_LEN + t * 32 + lg * 8;
      bf16x8 vf = *(const bf16x8*)vp;
      acc_o[0][dt] = mfma16(pf0, vf, acc_o[0][dt]);
      acc_o[1][dt] = mfma16(pf1, vf, acc_o[1][dt]);
    }
    __syncthreads();
    cur ^= 1;
  }

  // epilogue: reduce l across 16 ll-lanes, write partials
#pragma unroll
  for (int qg = 0; qg < 2; ++qg) {
#pragma unroll
    for (int j = 0; j < 4; ++j) {
      float l = l_run[qg][j];
      l += __shfl_xor(l, 1);
      l += __shfl_xor(l, 2);
      l += __shfl_xor(l, 4);
      l += __shfl_xor(l, 8);
      l_run[qg][j] = l;
    }
  }
  const size_t growb = (size_t)h * 8192 + (size_t)b * S_LEN + q0 + w * 32;
  if (ll == 0) {
#pragma unroll
    for (int qg = 0; qg < 2; ++qg)
#pragma unroll
      for (int j = 0; j < 4; ++j)
        Lpart[growb + qg * 16 + lg * 4 + j] = l_run[qg][j];
  }
#pragma unroll
  for (int qg = 0; qg < 2; ++qg)
#pragma unroll
    for (int dt = 0; dt < 16; ++dt)
#pragma unroll
      for (int j = 0; j < 4; ++j)
        Opart[(growb + qg * 16 + lg * 4 + j) * 256 + dt * 16 + ll] =
            f2b(acc_o[qg][dt][j]);
}

// sum the nslots chunk partials, normalize, emit per_head bf16
__global__ void combine_kernel(const u16* __restrict__ Opart,
                               const float* __restrict__ Lpart,
                               u16* __restrict__ ph, int nslots) {
  const int r = blockIdx.x;
  const int d = threadIdx.x;
  float o = 0.f, l = 0.f;
  for (int s = 0; s < nslots; ++s) {
    l += Lpart[(size_t)s * 8192 + r];
    o += b2f(Opart[((size_t)s * 8192 + r) * 256 + d]);
  }
  ph[(size_t)r * 256 + d] = f2b(o / l);
}

extern "C" void kernel_launch(void* const* d_in, const int* in_sizes, int n_in,
                              void* d_out, int out_size, void* d_ws, size_t ws_size,
                              hipStream_t stream) {
  const float* q = (const float*)d_in[0];
  const float* k = (const float*)d_in[1];
  const float* v = (const float*)d_in[2];
  const int* mask = (const int*)d_in[3];
  const float* Wq = (const float*)d_in[4];
  const float* bq = (const float*)d_in[5];
  const float* Wk = (const float*)d_in[6];
  const float* bk = (const float*)d_in[7];
  const float* Wv = (const float*)d_in[8];
  const float* bv = (const float*)d_in[9];
  const float* Wo = (const float*)d_in[10];
  const float* bo = (const float*)d_in[11];

  char* ws = (char*)d_ws;
  u16* qh = (u16*)(ws + 0);              //  4 MiB [2][4096][256]; reused as ph
  u16* kh = (u16*)(ws + 4194304);        //  4 MiB [2][4096][256]
  u16* vhT = (u16*)(ws + 8388608);       //  4 MiB [2][256][4096] (transposed)
  u16* WoS = (u16*)(ws + 12582912);      //  128 KiB [256][256]
  u32* mb = (u32*)(ws + 12713984);       //  4 MiB bitmask [2][4096][128] u32
  u16* Op = (u16*)(ws + 16908288);       // [nslots][8192][256] bf16 partials
  // z=16 needs Op 64 MiB + Lp 512 KiB -> ws >= 84541440; else fall back z=8
  int nslots = (ws_size >= 84541440u) ? 16 : 8;
  float* Lp = (float*)(ws + 16908288 + (size_t)nslots * 8192 * 256 * 2);
  int ckv = S_LEN / nslots, ntiles = ckv / 32;

  dim3 blk(256);
  gemm_nt_kernel<1, 0, 1><<<dim3(128, 4, 1), blk, 0, stream>>>(
      q, Wq, qh, bq, 0.0625f, 8192, 256, 256, 256, 256, 256, 0, 0, 0);
  gemm_nt_kernel<1, 0, 1><<<dim3(128, 4, 1), blk, 0, stream>>>(
      k, Wk, kh, bk, 1.0f, 8192, 256, 264, 264, 264, 256, 0, 0, 0);
  gemm_nt_kernel<1, 0, 2><<<dim3(4, 64, 2), blk, 0, stream>>>(
      Wv, v, vhT, bv, 1.0f, 256, 4096, 256, 256, 256, 4096,
      0, (long)4096 * 256, (long)256 * 4096);
  wos_kernel<<<dim3(256), blk, 0, stream>>>(Wo, WoS);
  bitpack_kernel<<<dim3(2048), blk, 0, stream>>>(mask, mb);
  flash_kernel<<<dim3(64 * nslots), blk, 0, stream>>>(qh, kh, vhT, mb, Op, Lp,
                                                      ckv, ntiles);
  combine_kernel<<<dim3(8192), blk, 0, stream>>>(Op, Lp, qh, nslots);
  gemm_nt_kernel<0, 1, 1><<<dim3(128, 4, 1), blk, 0, stream>>>(
      qh, WoS, d_out, bo, 1.0f, 8192, 256, 256, 256, 256, 256, 0, 0, 0);
}

// Round 6
// 137.197 us; speedup vs baseline: 2.9201x; 2.7814x over previous
//
#include <hip/hip_runtime.h>

typedef unsigned short u16;
typedef unsigned int u32;
typedef unsigned long long u64;
typedef __bf16 bf16x8 __attribute__((ext_vector_type(8)));
typedef float f32x4 __attribute__((ext_vector_type(4)));

#define S_LEN 4096
#define DM 256

__device__ __forceinline__ u16 f2b(float f) {
  u32 u = __builtin_bit_cast(u32, f);
  u = (u + 0x7FFFu + ((u >> 16) & 1u)) >> 16;
  return (u16)u;
}
__device__ __forceinline__ float b2f(u16 b) {
  return __builtin_bit_cast(float, (u32)b << 16);
}

__device__ __forceinline__ f32x4 mfma16(bf16x8 a, bf16x8 b, f32x4 c) {
  return __builtin_amdgcn_mfma_f32_16x16x32_bf16(a, b, c, 0, 0, 0);
}

// async 16B global->LDS (lane writes lds_base + lane*16)
__device__ __forceinline__ void gl_lds16(const u16* g, u16* l) {
  __builtin_amdgcn_global_load_lds(
      (const __attribute__((address_space(1))) u32*)g,
      (__attribute__((address_space(3))) u32*)l, 16, 0, 0);
}

#define SB() __builtin_amdgcn_sched_barrier(0)

// C[M][N] = (A[M][K] @ B[N][K]^T + bias) * scale   (NT gemm, K contiguous both sides)
template <int TIN_F32, int TOUT_F32, int BIAS_MODE>
__global__ __launch_bounds__(256, 2) void gemm_nt_kernel(
    const void* __restrict__ Ap, const void* __restrict__ Bp,
    void* __restrict__ Cp, const float* __restrict__ bias, float scale,
    int M, int N, int K, int lda, int ldb, int ldc,
    long sA, long sB, long sC) {
  __shared__ u16 As[64][72];
  __shared__ u16 Bs[64][72];
  const int tid = threadIdx.x;
  const int w = tid >> 6, ln = tid & 63, lg = ln >> 4, ll = ln & 15;
  const int m0 = blockIdx.x * 64, n0 = blockIdx.y * 64;
  const long zA = (long)blockIdx.z * sA, zB = (long)blockIdx.z * sB,
             zC = (long)blockIdx.z * sC;

  const f32x4 fzero = {0.f, 0.f, 0.f, 0.f};
  f32x4 acc[4];
#pragma unroll
  for (int i = 0; i < 4; ++i) acc[i] = fzero;

  const int srow = tid >> 2, scb = (tid & 3) * 16;
  const int nk = (K + 63) >> 6;
  for (int kc = 0; kc < nk; ++kc) {
    const int k0 = kc * 64;
    if (TIN_F32) {
      {
        const float* src = (const float*)Ap + zA + (size_t)(m0 + srow) * lda + k0 + scb;
        u16 t[16];
        if (k0 + 64 <= K) {
#pragma unroll
          for (int i = 0; i < 16; ++i) t[i] = f2b(src[i]);
        } else {
#pragma unroll
          for (int i = 0; i < 16; ++i) {
            int gk = k0 + scb + i;
            t[i] = (gk < K) ? f2b(src[i]) : (u16)0;
          }
        }
#pragma unroll
        for (int i = 0; i < 16; ++i) As[srow][scb + i] = t[i];
      }
      {
        const float* src = (const float*)Bp + zB + (size_t)(n0 + srow) * ldb + k0 + scb;
        u16 t[16];
        if (k0 + 64 <= K) {
#pragma unroll
          for (int i = 0; i < 16; ++i) t[i] = f2b(src[i]);
        } else {
#pragma unroll
          for (int i = 0; i < 16; ++i) {
            int gk = k0 + scb + i;
            t[i] = (gk < K) ? f2b(src[i]) : (u16)0;
          }
        }
#pragma unroll
        for (int i = 0; i < 16; ++i) Bs[srow][scb + i] = t[i];
      }
    } else {
      const u16* srcA = (const u16*)Ap + zA + (size_t)(m0 + srow) * lda + k0 + scb;
      *(bf16x8*)&As[srow][scb] = *(const bf16x8*)srcA;
      *(bf16x8*)&As[srow][scb + 8] = *(const bf16x8*)(srcA + 8);
      const u16* srcB = (const u16*)Bp + zB + (size_t)(n0 + srow) * ldb + k0 + scb;
      *(bf16x8*)&Bs[srow][scb] = *(const bf16x8*)srcB;
      *(bf16x8*)&Bs[srow][scb + 8] = *(const bf16x8*)(srcB + 8);
    }
    __syncthreads();
#pragma unroll
    for (int ks = 0; ks < 2; ++ks) {
      bf16x8 af = *(const bf16x8*)&As[w * 16 + ll][ks * 32 + lg * 8];
#pragma unroll
      for (int ct = 0; ct < 4; ++ct) {
        bf16x8 bfr = *(const bf16x8*)&Bs[ct * 16 + ll][ks * 32 + lg * 8];
        acc[ct] = mfma16(af, bfr, acc[ct]);
      }
    }
    __syncthreads();
  }

#pragma unroll
  for (int ct = 0; ct < 4; ++ct) {
#pragma unroll
    for (int j = 0; j < 4; ++j) {
      int row = m0 + w * 16 + lg * 4 + j;
      int col = n0 + ct * 16 + ll;
      float v = acc[ct][j];
      if (BIAS_MODE == 1) v += bias[col];
      if (BIAS_MODE == 2) v += bias[row];
      v *= scale;
      if (TOUT_F32)
        ((float*)Cp)[zC + (size_t)row * ldc + col] = v;
      else
        ((u16*)Cp)[zC + (size_t)row * ldc + col] = f2b(v);
    }
  }
}

// Wo_sum[d][e] = sum_h Wo[d][h*256+e]  (bf16)
__global__ void wos_kernel(const float* __restrict__ Wo, u16* __restrict__ WoS) {
  int d = blockIdx.x, e = threadIdx.x;
  const float* p = Wo + (size_t)d * 1024;
  WoS[(size_t)d * 256 + e] = f2b(p[e] + p[256 + e] + p[512 + e] + p[768 + e]);
}

// mask int32 -> bitmask (bit i of u64 group g of row r = mask[r][64g+i] != 0)
__global__ __launch_bounds__(256) void bitpack_kernel(const int* __restrict__ mask,
                                                      u32* __restrict__ mb) {
  const int ln = threadIdx.x & 63;
  const int gw = (int)((blockIdx.x * 256 + threadIdx.x) >> 6);
  const int nw = gridDim.x * 4;
  u64* mb64 = (u64*)mb;
  for (int it = gw; it < 131072; it += nw) {
    const int* p = mask + (size_t)it * 256 + ln;
    int v0 = p[0], v1 = p[64], v2 = p[128], v3 = p[192];
    u64 b0 = __ballot(v0 != 0);
    u64 b1 = __ballot(v1 != 0);
    u64 b2 = __ballot(v2 != 0);
    u64 b3 = __ballot(v3 != 0);
    if (ln < 4) {
      u64 val = ln == 0 ? b0 : (ln == 1 ? b1 : (ln == 2 ? b2 : b3));
      mb64[(size_t)it * 4 + ln] = val;
    }
  }
}

// Flash attention, no-max softmax, bitmask, K+V LDS-staged (R3 structure) with
// a counted-vmcnt software pipeline: raw s_barrier (no vmcnt(0) drain in the
// steady loop). FIFO discipline per tile t: outstanding = [mask(t):8,
// stage(t+1):8]; QK runs on resident buf; vmcnt(8) releases mask(t);
// end-read barrier; issue mask(t+1) then stage(t+2); vmcnt(16) completes
// stage(t+1) only; raw barrier. V source pre-swizzled (cc^=(row>>1)&3) to
// kill the 8-way PV bank conflict.
__global__ __launch_bounds__(256, 2) void flash_kernel(
    const u16* __restrict__ qh, const u16* __restrict__ kh,
    const u16* __restrict__ vhT, const u32* __restrict__ mb,
    u16* __restrict__ Opart, float* __restrict__ Lpart) {
  __shared__ u16 kh_s[2][32 * 256];  // 32KB dbuf, chunk swz: cc ^= row&7
  __shared__ u16 vs_s[2][256 * 32];  // 32KB dbuf, chunk swz: cc ^= (row>>1)&3
  __shared__ u16 p_s[4][32][40];     // 10KB per-wave P tile

  const int tid = threadIdx.x;
  const int w = tid >> 6, ln = tid & 63, lg = ln >> 4, ll = ln & 15;
  const int wg = ((int)blockIdx.x & 7) * 64 + ((int)blockIdx.x >> 3);
  const int q0 = (wg & 31) * 128;
  const int b = (wg >> 5) & 1;
  const int h = wg >> 6;  // kv chunk (512 each)

  bf16x8 qf[2][8];
#pragma unroll
  for (int qg = 0; qg < 2; ++qg) {
    const u16* qp = qh + (size_t)(b * S_LEN + q0 + w * 32 + qg * 16 + ll) * DM + lg * 8;
#pragma unroll
    for (int ks = 0; ks < 8; ++ks) qf[qg][ks] = *(const bf16x8*)(qp + ks * 32);
  }

  const f32x4 fzero = {0.f, 0.f, 0.f, 0.f};
  f32x4 acc_o[2][16];
#pragma unroll
  for (int qg = 0; qg < 2; ++qg)
#pragma unroll
    for (int i = 0; i < 16; ++i) acc_o[qg][i] = fzero;
  float l_run[2][4] = {{0.f, 0.f, 0.f, 0.f}, {0.f, 0.f, 0.f, 0.f}};

  const u16* kbase = kh + (size_t)(b * S_LEN + h * 512) * DM;
  const u16* vbase = vhT + (size_t)b * DM * S_LEN + h * 512;
  const u32* mbase = mb + (size_t)(b * S_LEN + q0 + w * 32) * 128 + h * 16;

  // 8 DMA issues per lane: 4 K-chunks + 4 V-chunks, pre-swizzled sources,
  // linear LDS destinations.
  auto stage = [&](int t, int buf) {
#pragma unroll
    for (int i = 0; i < 4; ++i) {
      int c = i * 256 + tid;
      int row = c >> 5, ccl = c & 31;
      int ccg = ccl ^ (row & 7);
      gl_lds16(kbase + (size_t)(t * 32 + row) * DM + ccg * 8,
               &kh_s[buf][(i * 256 + w * 64) * 8]);
    }
#pragma unroll
    for (int i = 0; i < 4; ++i) {
      int c = i * 256 + tid;
      int row = c >> 2, ccl = c & 3;
      int ccg = ccl ^ ((row >> 1) & 3);
      gl_lds16(vbase + (size_t)row * S_LEN + t * 32 + ccg * 8,
               &vs_s[buf][(i * 256 + w * 64) * 8]);
    }
  };

  u32 mwc[2][4], mwn[2][4];
  auto loadmask = [&](int t, u32 out[2][4]) {
#pragma unroll
    for (int qg = 0; qg < 2; ++qg)
#pragma unroll
      for (int j = 0; j < 4; ++j)
        out[qg][j] = mbase[(size_t)(qg * 16 + lg * 4 + j) * 128 + t];
  };

  // ---- prologue ----
  stage(0, 0);  // 8 vm
  asm volatile("s_waitcnt vmcnt(0)" ::: "memory");
  __builtin_amdgcn_s_barrier();
  SB();
  loadmask(0, mwc);  // 8 vm   queue [m0:8]
  SB();
  stage(1, 1);  // 8 vm   queue [m0:8, s1:8]
  SB();

  int cur = 0;

#define QK_PHASE()                                                            \
  f32x4 accs[2][2];                                                           \
  accs[0][0] = fzero; accs[0][1] = fzero;                                     \
  accs[1][0] = fzero; accs[1][1] = fzero;                                     \
  __builtin_amdgcn_s_setprio(1);                                              \
  _Pragma("unroll") for (int ks = 0; ks < 8; ++ks) {                          \
    _Pragma("unroll") for (int half = 0; half < 2; ++half) {                  \
      int krow = half * 16 + ll;                                              \
      bf16x8 kf = *(const bf16x8*)&kh_s[cur][krow * 256 +                     \
                                            (((ks * 4 + lg) ^ (krow & 7)) << 3)]; \
      accs[0][half] = mfma16(qf[0][ks], kf, accs[0][half]);                   \
      accs[1][half] = mfma16(qf[1][ks], kf, accs[1][half]);                   \
    }                                                                         \
  }                                                                           \
  __builtin_amdgcn_s_setprio(0);

#define SM_PV_PHASE()                                                         \
  _Pragma("unroll") for (int qg = 0; qg < 2; ++qg) {                          \
    _Pragma("unroll") for (int j = 0; j < 4; ++j) {                           \
      u32 m = mwc[qg][j];                                                     \
      float p0 = ((m >> ll) & 1u) ? __expf(accs[qg][0][j]) : 0.f;             \
      float p1 = ((m >> (16 + ll)) & 1u) ? __expf(accs[qg][1][j]) : 0.f;      \
      l_run[qg][j] += p0 + p1;                                                \
      int r = qg * 16 + lg * 4 + j;                                           \
      p_s[w][r][ll] = f2b(p0);                                                \
      p_s[w][r][16 + ll] = f2b(p1);                                           \
    }                                                                         \
  }                                                                           \
  bf16x8 pf0 = *(const bf16x8*)&p_s[w][ll][lg * 8];                           \
  bf16x8 pf1 = *(const bf16x8*)&p_s[w][16 + ll][lg * 8];                      \
  __builtin_amdgcn_s_setprio(1);                                              \
  _Pragma("unroll") for (int dt = 0; dt < 16; ++dt) {                         \
    int vrow = dt * 16 + ll;                                                  \
    bf16x8 vf = *(const bf16x8*)&vs_s[cur][vrow * 32 +                        \
                                          ((lg ^ ((vrow >> 1) & 3)) << 3)];   \
    acc_o[0][dt] = mfma16(pf0, vf, acc_o[0][dt]);                             \
    acc_o[1][dt] = mfma16(pf1, vf, acc_o[1][dt]);                             \
  }                                                                           \
  __builtin_amdgcn_s_setprio(0);

#define COPY_MW()                                                             \
  _Pragma("unroll") for (int qg = 0; qg < 2; ++qg)                            \
  _Pragma("unroll") for (int j = 0; j < 4; ++j) mwc[qg][j] = mwn[qg][j];

  // ---- steady loop: t = 0..13 (stage(t+2) exists) ----
#pragma unroll 1
  for (int t = 0; t < 14; ++t) {
    {
      QK_PHASE();
      asm volatile("s_waitcnt vmcnt(8)" ::: "memory");  // mask(t) ready
      SB();
      SM_PV_PHASE();
    }
    SB();
    __builtin_amdgcn_s_barrier();  // all waves done reading buf[cur]
    SB();
    loadmask(t + 1, mwn);  // 8 vm
    SB();
    stage(t + 2, cur);  // 8 vm into buf[cur]
    SB();
    asm volatile("s_waitcnt vmcnt(16)" ::: "memory");  // stage(t+1) ready
    SB();
    __builtin_amdgcn_s_barrier();
    SB();
    COPY_MW();
    cur ^= 1;
  }

  // ---- t = 14: no stage(16) ----
  {
    {
      QK_PHASE();
      asm volatile("s_waitcnt vmcnt(8)" ::: "memory");
      SB();
      SM_PV_PHASE();
    }
    SB();
    __builtin_amdgcn_s_barrier();
    SB();
    loadmask(15, mwn);  // queue [s15:8, m15:8]
    SB();
    asm volatile("s_waitcnt vmcnt(8)" ::: "memory");  // stage(15) ready
    SB();
    __builtin_amdgcn_s_barrier();
    SB();
    COPY_MW();
    cur ^= 1;
  }

  // ---- t = 15: final ----
  {
    QK_PHASE();
    asm volatile("s_waitcnt vmcnt(0)" ::: "memory");  // mask(15) ready
    SB();
    SM_PV_PHASE();
  }

  // ---- epilogue: reduce l across 16 ll-lanes, write partials ----
#pragma unroll
  for (int qg = 0; qg < 2; ++qg) {
#pragma unroll
    for (int j = 0; j < 4; ++j) {
      float l = l_run[qg][j];
      l += __shfl_xor(l, 1);
      l += __shfl_xor(l, 2);
      l += __shfl_xor(l, 4);
      l += __shfl_xor(l, 8);
      l_run[qg][j] = l;
    }
  }
  const size_t growb = (size_t)h * 8192 + (size_t)b * S_LEN + q0 + w * 32;
  if (ll == 0) {
#pragma unroll
    for (int qg = 0; qg < 2; ++qg)
#pragma unroll
      for (int j = 0; j < 4; ++j)
        Lpart[growb + qg * 16 + lg * 4 + j] = l_run[qg][j];
  }
#pragma unroll
  for (int qg = 0; qg < 2; ++qg)
#pragma unroll
    for (int dt = 0; dt < 16; ++dt)
#pragma unroll
      for (int j = 0; j < 4; ++j)
        Opart[(growb + qg * 16 + lg * 4 + j) * 256 + dt * 16 + ll] =
            f2b(acc_o[qg][dt][j]);
}

// sum the 8 chunk partials, normalize, emit per_head bf16
__global__ void combine_kernel(const u16* __restrict__ Opart,
                               const float* __restrict__ Lpart,
                               u16* __restrict__ ph) {
  const int r = blockIdx.x;
  const int d = threadIdx.x;
  float o = 0.f, l = 0.f;
#pragma unroll
  for (int s = 0; s < 8; ++s) {
    l += Lpart[(size_t)s * 8192 + r];
    o += b2f(Opart[((size_t)s * 8192 + r) * 256 + d]);
  }
  ph[(size_t)r * 256 + d] = f2b(o / l);
}

extern "C" void kernel_launch(void* const* d_in, const int* in_sizes, int n_in,
                              void* d_out, int out_size, void* d_ws, size_t ws_size,
                              hipStream_t stream) {
  const float* q = (const float*)d_in[0];
  const float* k = (const float*)d_in[1];
  const float* v = (const float*)d_in[2];
  const int* mask = (const int*)d_in[3];
  const float* Wq = (const float*)d_in[4];
  const float* bq = (const float*)d_in[5];
  const float* Wk = (const float*)d_in[6];
  const float* bk = (const float*)d_in[7];
  const float* Wv = (const float*)d_in[8];
  const float* bv = (const float*)d_in[9];
  const float* Wo = (const float*)d_in[10];
  const float* bo = (const float*)d_in[11];

  char* ws = (char*)d_ws;
  u16* qh = (u16*)(ws + 0);              //  4 MiB [2][4096][256]; reused as ph
  u16* kh = (u16*)(ws + 4194304);        //  4 MiB [2][4096][256]
  u16* vhT = (u16*)(ws + 8388608);       //  4 MiB [2][256][4096] (transposed)
  u16* WoS = (u16*)(ws + 12582912);      //  128 KiB [256][256]
  u32* mb = (u32*)(ws + 12713984);       //  4 MiB bitmask [2][4096][128] u32
  u16* Op = (u16*)(ws + 16908288);       // 32 MiB [8][8192][256] bf16 partials
  float* Lp = (float*)(ws + 50462720);   // 256 KiB [8][8192] f32 row sums

  dim3 blk(256);
  gemm_nt_kernel<1, 0, 1><<<dim3(128, 4, 1), blk, 0, stream>>>(
      q, Wq, qh, bq, 0.0625f, 8192, 256, 256, 256, 256, 256, 0, 0, 0);
  gemm_nt_kernel<1, 0, 1><<<dim3(128, 4, 1), blk, 0, stream>>>(
      k, Wk, kh, bk, 1.0f, 8192, 256, 264, 264, 264, 256, 0, 0, 0);
  gemm_nt_kernel<1, 0, 2><<<dim3(4, 64, 2), blk, 0, stream>>>(
      Wv, v, vhT, bv, 1.0f, 256, 4096, 256, 256, 256, 4096,
      0, (long)4096 * 256, (long)256 * 4096);
  wos_kernel<<<dim3(256), blk, 0, stream>>>(Wo, WoS);
  bitpack_kernel<<<dim3(2048), blk, 0, stream>>>(mask, mb);
  flash_kernel<<<dim3(512), blk, 0, stream>>>(qh, kh, vhT, mb, Op, Lp);
  combine_kernel<<<dim3(8192), blk, 0, stream>>>(Op, Lp, qh);
  gemm_nt_kernel<0, 1, 1><<<dim3(128, 4, 1), blk, 0, stream>>>(
      qh, WoS, d_out, bo, 1.0f, 8192, 256, 256, 256, 256, 256, 0, 0, 0);
}